// Round 8
// baseline (638.512 us; speedup 1.0000x reference)
//
#include <hip/hip_runtime.h>

#define HW 96
#define NPIX 9216      // 96*96
#define NCH 128
#define NB 16
#define HP 98          // haloed plane dim (coords -1..96)

// ---------------- channel mix: mixed[b,c,p] = sum_i lin[c,i] * x[b,i,p] ----------------
// R13: wave = 32 ch x 128 px (2 px/lane), block = 256 thr (4 waves) covering all
// 128 ch of ONE 128-px tile. Grid 72x16 = 1152 (4.5 blocks/CU, ~11% imbalance).
// WHY: R12's null (depth 8->16 identical) shows exposed stall scales PER LOAD
// (~62cy), not per batch -- FMA:load ratio is set by the tile. In R5/R12 all 8
// waves of a block span the SAME px tile -> the 64KB x-tile (>32KB L1) streams
// 8x redundantly through VMEM/L1: 590MB in 70us = 33 B/cy/CU = ~50% of L1 peak,
// matching VALU ~50% (phase-locked convoy, both pipes half-idle). 32ch/wave
// halves redundancy (4x) and doubles FMA:load to 64:1 -> predict duty ~65%.
// acc 64 + xv 16 ~ 90 VGPR; lb(256,4) = 128-VGPR cap (R10 lesson: tight caps
// spill; watch WRITE_SIZE=73.7MB to confirm clean).
// DEAD ENDS (measured): R6 ping-pong 92us; R7 192px retile 80us; R9 ch-split
// across blocks 4x HBM fetch 96us; R10 LDS+64cap spill 283us; R11 LDS staging
// 129us (ds+s_load share lgkmcnt); R12 depth-16 null.
template<int K>
__global__ __launch_bounds__(256, 4) void mix_kernel(const float* __restrict__ x,
                                                     const float* __restrict__ lin,
                                                     float* __restrict__ mixed) {
    const int b    = blockIdx.y;
    const int lane = threadIdx.x & 63;
    const int p    = blockIdx.x * 128 + lane * 2;
    const int c0   = __builtin_amdgcn_readfirstlane((threadIdx.x >> 6) * 32);
    const float* xb = x + (size_t)b * K * NPIX + p;
    const float* lr = lin + c0 * K;

    float2 acc[32];
    #pragma unroll
    for (int c = 0; c < 32; ++c) acc[c] = float2{0.f, 0.f};

    for (int k0 = 0; k0 < K; k0 += 8) {
        float2 xv[8];
        #pragma unroll
        for (int j = 0; j < 8; ++j)
            xv[j] = *(const float2*)&xb[(size_t)(k0 + j) * NPIX];
        #pragma unroll
        for (int c = 0; c < 32; ++c) {
            const float* lc = lr + c * K + k0;     // wave-uniform -> s_load
            #pragma unroll
            for (int j = 0; j < 8; ++j) {
                acc[c].x = fmaf(lc[j], xv[j].x, acc[c].x);
                acc[c].y = fmaf(lc[j], xv[j].y, acc[c].y);
            }
        }
    }
    float* ob = mixed + (size_t)b * NCH * NPIX + p;
    #pragma unroll
    for (int c = 0; c < 32; ++c)
        *(float2*)&ob[(size_t)(c0 + c) * NPIX] = acc[c];
}

__device__ inline float clamp01(float z) { return fminf(fmaxf(z, 0.f), 1.f); }

// ---------------- bilinear affine sample (zero-halo LDS plane) ----------------
// Plane staged into LDS with a 1px zero border (coords -1..96). ix clamped to
// [-1,96]: every out-of-range tap then reads a zero cell with the correct
// weight, eliminating all validity masks. Box-sample-of-ones factorizes:
// bw = min(clamp01(bx+1), clamp01(96-bx)) * (same in y). 2-lerp form = 6 FMA.
// 512 threads (R6 evidence: helped): LDS 38.4 KB -> 4 blocks/CU, 32 waves/CU.
template<bool RES, bool POOL>
__global__ __launch_bounds__(512) void sample_kernel(const float* __restrict__ mixed,
                                                     const float* __restrict__ geo,
                                                     const float* __restrict__ box,
                                                     float* __restrict__ out,
                                                     float* __restrict__ pooled) {
    __shared__ float m[HP * HP];           // 38.4 KB -> 4 blocks/CU, 32 waves/CU
    const int c = blockIdx.x;
    const int b = blockIdx.y;
    const int t = threadIdx.x;
    // zero only the halo border (interior is fully overwritten by the fill)
    if (t < HP) {                           // top & bottom rows
        m[t] = 0.f;
        m[(HP - 1) * HP + t] = 0.f;
    } else if (t < HP + 96) {               // left & right columns (rows 1..96)
        const int h = t - HP + 1;
        m[h * HP] = 0.f;
        m[h * HP + HP - 1] = 0.f;
    }
    const float* src = mixed + ((size_t)b * NCH + c) * NPIX;
    #pragma unroll
    for (int r = 0; r < NPIX / 512; ++r) {
        const int idx = r * 512 + t;
        const int h = idx / 96, w = idx - (idx / 96) * 96;
        m[(h + 1) * HP + (w + 1)] = src[idx];
    }
    const float* gth = geo + c * 6;
    const float* bth = box + c * 6;
    const float g0 = gth[0], g1 = gth[1], g3 = gth[3], g4 = gth[4];
    const float gcx = 48.f * gth[2] - 47.5f * (g0 + g1) + 47.5f;
    const float gcy = 48.f * gth[5] - 47.5f * (g3 + g4) + 47.5f;
    const float b0 = bth[0], b1 = bth[1], b3 = bth[3], b4 = bth[4];
    const float bcx = 48.f * bth[2] - 47.5f * (b0 + b1) + 47.5f;
    const float bcy = 48.f * bth[5] - 47.5f * (b3 + b4) + 47.5f;
    float* o = out + ((size_t)b * NCH + c) * NPIX;
    __syncthreads();
    float psum = 0.f;
    #pragma unroll 6
    for (int r = 0; r < NPIX / 512; ++r) {
        const int p = r * 512 + t;
        const int h = p / 96, w = p - (p / 96) * 96;
        const float fw = (float)w, fh = (float)h;
        float ix = fmaf(g0, fw, fmaf(g1, fh, gcx));
        float iy = fmaf(g3, fw, fmaf(g4, fh, gcy));
        ix = fminf(fmaxf(ix, -1.f), 96.f);
        iy = fminf(fmaxf(iy, -1.f), 96.f);
        const float x0f = floorf(ix), y0f = floorf(iy);
        const float fx = ix - x0f, fy = iy - y0f;
        const int base = ((int)y0f + 1) * HP + ((int)x0f + 1);
        const float m00 = m[base],      m01 = m[base + 1];
        const float m10 = m[base + HP], m11 = m[base + HP + 1];
        const float mx0 = fmaf(fx, m01 - m00, m00);
        const float mx1 = fmaf(fx, m11 - m10, m10);
        float v = fmaf(fy, mx1 - mx0, mx0);
        const float bx = fmaf(b0, fw, fmaf(b1, fh, bcx));
        const float by = fmaf(b3, fw, fmaf(b4, fh, bcy));
        const float Xs = fminf(clamp01(bx + 1.f), clamp01(96.f - bx));
        const float Ys = fminf(clamp01(by + 1.f), clamp01(96.f - by));
        v *= Xs * Ys;
        if (RES) v += o[p];
        o[p] = v;
        if (POOL) psum += v;
    }
    if (POOL) {
        #pragma unroll
        for (int off = 32; off > 0; off >>= 1) psum += __shfl_down(psum, off, 64);
        __shared__ float red[8];
        if ((t & 63) == 0) red[t >> 6] = psum;
        __syncthreads();
        if (t == 0) {
            float s = 0.f;
            #pragma unroll
            for (int i = 0; i < 8; ++i) s += red[i];
            pooled[b * NCH + c] = s * (1.f / (float)NPIX);
        }
    }
}

// ---------------- mean pool (fallback when ws has no room for pooled) ----------------
__global__ __launch_bounds__(256) void pool_kernel(const float* __restrict__ feat,
                                                   float* __restrict__ pooled) {
    const int bc = blockIdx.x;           // b*128 + c
    const float4* f = (const float4*)(feat + (size_t)bc * NPIX);
    float s = 0.f;
    for (int i = threadIdx.x; i < NPIX / 4; i += 256) {
        const float4 v = f[i];
        s += (v.x + v.y) + (v.z + v.w);
    }
    #pragma unroll
    for (int off = 32; off > 0; off >>= 1) s += __shfl_down(s, off, 64);
    __shared__ float red[4];
    if ((threadIdx.x & 63) == 0) red[threadIdx.x >> 6] = s;
    __syncthreads();
    if (threadIdx.x == 0)
        pooled[bc] = (red[0] + red[1] + red[2] + red[3]) * (1.f / (float)NPIX);
}

// ---------------- dense: logits[b,n] = pooled[b,:] . W[n,:] + bias[n] ----------------
__global__ __launch_bounds__(256) void dense_kernel(const float* __restrict__ pooled,
                                                    const float* __restrict__ Wt,
                                                    const float* __restrict__ bias,
                                                    float* __restrict__ out) {
    const int idx = blockIdx.x * 256 + threadIdx.x;
    if (idx >= NB * 1000) return;
    const int b = idx / 1000, n = idx - b * 1000;
    float acc = bias[n];
    const float* p = pooled + b * NCH;
    const float* wr = Wt + n * NCH;
    #pragma unroll 4
    for (int c = 0; c < NCH; ++c) acc = fmaf(p[c], wr[c], acc);
    out[idx] = acc;
}

extern "C" void kernel_launch(void* const* d_in, const int* in_sizes, int n_in,
                              void* d_out, int out_size, void* d_ws, size_t ws_size,
                              hipStream_t stream) {
    const float* x       = (const float*)d_in[0];   // [16,64,96,96]
    const float* in_geo  = (const float*)d_in[1];   // [128,2,3]
    const float* in_box  = (const float*)d_in[2];   // [128,2,3]
    const float* in_lin  = (const float*)d_in[3];   // [128,64]
    const float* lay_geo = (const float*)d_in[4];   // [4,128,2,3]
    const float* lay_box = (const float*)d_in[5];   // [4,128,2,3]
    const float* lay_lin = (const float*)d_in[6];   // [4,128,128]
    const float* dense_w = (const float*)d_in[7];   // [1000,128]
    const float* dense_b = (const float*)d_in[8];   // [1000]

    float* out  = (float*)d_out;
    float* feat = out + NB * 1000;                  // [16,128,96,96] lives in d_out
    float* mixed = (float*)d_ws;                    // 75.5 MB scratch

    const size_t mixedFloats = (size_t)NB * NCH * NPIX;
    const bool fusedPool = ws_size >= (mixedFloats + NB * NCH) * sizeof(float);
    float* pooled = fusedPool ? (float*)d_ws + mixedFloats : (float*)d_ws;

    const dim3 mixGrid(NPIX / 128, NB);             // 72 x 16 = 1152 blocks of 256
    const dim3 smpGrid(NCH, NB);

    mix_kernel<64><<<mixGrid, 256, 0, stream>>>(x, in_lin, mixed);
    sample_kernel<false, false><<<smpGrid, 512, 0, stream>>>(mixed, in_geo, in_box, feat, pooled);
    for (int i = 0; i < 3; ++i) {
        mix_kernel<128><<<mixGrid, 256, 0, stream>>>(feat, lay_lin + i * NCH * NCH, mixed);
        sample_kernel<true, false><<<smpGrid, 512, 0, stream>>>(mixed, lay_geo + i * NCH * 6,
                                                                lay_box + i * NCH * 6, feat, pooled);
    }
    mix_kernel<128><<<mixGrid, 256, 0, stream>>>(feat, lay_lin + 3 * NCH * NCH, mixed);
    if (fusedPool) {
        sample_kernel<true, true><<<smpGrid, 512, 0, stream>>>(mixed, lay_geo + 3 * NCH * 6,
                                                               lay_box + 3 * NCH * 6, feat, pooled);
    } else {
        sample_kernel<true, false><<<smpGrid, 512, 0, stream>>>(mixed, lay_geo + 3 * NCH * 6,
                                                                lay_box + 3 * NCH * 6, feat, pooled);
        pool_kernel<<<NB * NCH, 256, 0, stream>>>(feat, pooled);
    }
    dense_kernel<<<(NB * 1000 + 255) / 256, 256, 0, stream>>>(pooled, dense_w, dense_b, out);
}

// Round 9
// 488.520 us; speedup vs baseline: 1.3070x; 1.3070x over previous
//
#include <hip/hip_runtime.h>
#include <stdint.h>

#define HW 96
#define NPIX 9216      // 96*96
#define NCH 128
#define NB 16
#define HP 98          // haloed plane dim (coords -1..96)

using bf16x8 = __attribute__((ext_vector_type(8))) short;   // 8 bf16 (4 VGPR) MFMA operand
using f32x4  = __attribute__((ext_vector_type(4))) float;   // MFMA accumulator

// pack fp32 -> (bf16_hi << 16) | bf16_lo, both RNE. hi+lo represents v to ~4e-6 rel.
__device__ inline uint32_t packbf(float v) {
    uint32_t u  = __float_as_uint(v);
    uint32_t rh = (u + 0x7FFFu + ((u >> 16) & 1u)) & 0xFFFF0000u;  // hi bf16, kept in fp32 position
    float    lo = v - __uint_as_float(rh);
    uint32_t ul = __float_as_uint(lo);
    uint32_t rl = ((ul + 0x7FFFu + ((ul >> 16) & 1u)) >> 16) & 0xFFFFu;
    return rh | rl;
}

// ---------------- tiny: pack lay_lin fp32 -> u32(hi|lo) ----------------
__global__ __launch_bounds__(256) void packlin_kernel(const float* __restrict__ lin,
                                                      uint32_t* __restrict__ linP, int n) {
    const int i = blockIdx.x * 256 + threadIdx.x;
    if (i < n) linP[i] = packbf(lin[i]);
}

// ---------------- fp32 channel mix (layer 0 / fallback) ----------------
// R5/R12 proven structure: no-LDS, block 512, tile 128px x 128ch, wave=16ch,
// lin wave-uniform s_load. 70us @K=128; used only for K=64 on the MFMA path.
template<int K>
__global__ __launch_bounds__(512, 4) void mix_kernel(const float* __restrict__ x,
                                                     const float* __restrict__ lin,
                                                     float* __restrict__ mixed) {
    const int b    = blockIdx.y;
    const int lane = threadIdx.x & 63;
    const int p    = blockIdx.x * 128 + lane * 2;
    const int c0   = __builtin_amdgcn_readfirstlane((threadIdx.x >> 6) * 16);
    const float* xb = x + (size_t)b * K * NPIX + p;
    const float* lr = lin + c0 * K;

    float2 acc[16];
    #pragma unroll
    for (int c = 0; c < 16; ++c) acc[c] = float2{0.f, 0.f};

    for (int k0 = 0; k0 < K; k0 += 8) {
        float2 xv[8];
        #pragma unroll
        for (int j = 0; j < 8; ++j)
            xv[j] = *(const float2*)&xb[(size_t)(k0 + j) * NPIX];
        #pragma unroll
        for (int c = 0; c < 16; ++c) {
            const float* lc = lr + c * K + k0;
            #pragma unroll
            for (int j = 0; j < 8; ++j) {
                acc[c].x = fmaf(lc[j], xv[j].x, acc[c].x);
                acc[c].y = fmaf(lc[j], xv[j].y, acc[c].y);
            }
        }
    }
    float* ob = mixed + (size_t)b * NCH * NPIX + p;
    #pragma unroll
    for (int c = 0; c < 16; ++c)
        *(float2*)&ob[(size_t)(c0 + c) * NPIX] = acc[c];
}

// ---------------- MFMA channel mix (K=128): mixed = lin * xP ----------------
// bf16 hi/lo split GEMM on 16x16x32 bf16 MFMA. Inputs pre-packed u32 (hi|lo):
// xP[b][k][p] (written in-place over `mixed` by the preceding sample), linP[c][k].
// Block 512 thr = 8 waves; wave = 16ch x 128px (8 N-tiles); all 128ch covered.
// x tile [128k x 128px] staged once in 64KB LDS, XOR-swizzled (px ^ ((k&0xC)<<2))
// -> quads land 2-way/bank = free (m136). Inner loop: LDS + regs only (no SMEM,
// no global -- R11's lgkmcnt lesson). Frag layout (cross-derived from tr_b16
// formula + verified D map): A lane: row=l&15, k=(e>>2)*16+(l>>4)*4+(e&3);
// B: col=l&15, same k(e); D: col=l&15, row=(l>>4)*4+r.
// In-place safe: block stages its whole read-set before the barrier; epilogue
// stores (same px stripe) happen strictly after.
__global__ __launch_bounds__(512, 2) void mix_mfma_kernel(const uint32_t* __restrict__ xP,
                                                          const uint32_t* __restrict__ lp,
                                                          float* __restrict__ mixed) {
    __shared__ uint32_t xs[128 * 128];     // 64KB -> 2 blocks/CU
    const int b   = blockIdx.y;
    const int px0 = blockIdx.x * 128;
    const int t   = threadIdx.x;

    // ---- stage packed x tile; swizzled store: xs[k*128 + (px ^ ((k&0xC)<<2))] ----
    const uint32_t* xb = xP + (size_t)b * NCH * NPIX + px0;
    #pragma unroll
    for (int i = 0; i < 8; ++i) {
        const int f4  = i * 512 + t;
        const int row = f4 >> 5;
        const int c4  = (f4 & 31) << 2;
        const uint4 v = *(const uint4*)&xb[(size_t)row * NPIX + c4];
        uint32_t* d = &xs[row * 128 + (c4 ^ ((row & 0xC) << 2))];
        d[0] = v.x; d[1] = v.y; d[2] = v.z; d[3] = v.w;
    }

    const int l  = t & 63;
    const int wv = t >> 6;           // 0..7 -> channel group
    const int c0 = wv * 16;
    const int lq = l >> 4;           // lane quadrant
    const int lr = l & 15;

    // ---- A fragments (lin hi/lo) for 4 K-steps, from packed linP[c][k] ----
    bf16x8 AH[4], AL[4];
    const uint32_t* lrow = lp + (size_t)(c0 + lr) * NCH;
    #pragma unroll
    for (int q = 0; q < 4; ++q) {
        const uint4 a0 = *(const uint4*)&lrow[q * 32 + lq * 4];        // elems 0-3 (k half 0)
        const uint4 a1 = *(const uint4*)&lrow[q * 32 + 16 + lq * 4];   // elems 4-7 (k half 1)
        union { uint32_t w[4]; bf16x8 v; } h, m;
        h.w[0] = (a0.x >> 16) | (a0.y & 0xFFFF0000u);
        h.w[1] = (a0.z >> 16) | (a0.w & 0xFFFF0000u);
        h.w[2] = (a1.x >> 16) | (a1.y & 0xFFFF0000u);
        h.w[3] = (a1.z >> 16) | (a1.w & 0xFFFF0000u);
        m.w[0] = (a0.x & 0xFFFFu) | (a0.y << 16);
        m.w[1] = (a0.z & 0xFFFFu) | (a0.w << 16);
        m.w[2] = (a1.x & 0xFFFFu) | (a1.y << 16);
        m.w[3] = (a1.z & 0xFFFFu) | (a1.w << 16);
        AH[q] = h.v; AL[q] = m.v;
    }

    f32x4 acc[8];
    #pragma unroll
    for (int n = 0; n < 8; ++n) acc[n] = f32x4{0.f, 0.f, 0.f, 0.f};

    __syncthreads();

    const int pswz = lq << 4;        // == ((k&0xC)<<2) for every k this lane touches
    #pragma unroll
    for (int q = 0; q < 4; ++q) {
        const int kb = q * 32 + lq * 4;
        #pragma unroll
        for (int np = 0; np < 4; ++np) {
            const int n0 = np * 2;
            bf16x8 BH0, BL0, BH1, BL1;
            #pragma unroll
            for (int s = 0; s < 2; ++s) {
                const int px = ((n0 + s) * 16 + lr) ^ pswz;
                const uint32_t u0 = xs[(kb + 0) * 128 + px];
                const uint32_t u1 = xs[(kb + 1) * 128 + px];
                const uint32_t u2 = xs[(kb + 2) * 128 + px];
                const uint32_t u3 = xs[(kb + 3) * 128 + px];
                const uint32_t u4 = xs[(kb + 16) * 128 + px];
                const uint32_t u5 = xs[(kb + 17) * 128 + px];
                const uint32_t u6 = xs[(kb + 18) * 128 + px];
                const uint32_t u7 = xs[(kb + 19) * 128 + px];
                union { uint32_t w[4]; bf16x8 v; } h, m;
                h.w[0] = (u0 >> 16) | (u1 & 0xFFFF0000u);
                h.w[1] = (u2 >> 16) | (u3 & 0xFFFF0000u);
                h.w[2] = (u4 >> 16) | (u5 & 0xFFFF0000u);
                h.w[3] = (u6 >> 16) | (u7 & 0xFFFF0000u);
                m.w[0] = (u0 & 0xFFFFu) | (u1 << 16);
                m.w[1] = (u2 & 0xFFFFu) | (u3 << 16);
                m.w[2] = (u4 & 0xFFFFu) | (u5 << 16);
                m.w[3] = (u6 & 0xFFFFu) | (u7 << 16);
                if (s == 0) { BH0 = h.v; BL0 = m.v; } else { BH1 = h.v; BL1 = m.v; }
            }
            acc[n0]     = __builtin_amdgcn_mfma_f32_16x16x32_bf16(AH[q], BH0, acc[n0],     0, 0, 0);
            acc[n0 + 1] = __builtin_amdgcn_mfma_f32_16x16x32_bf16(AH[q], BH1, acc[n0 + 1], 0, 0, 0);
            acc[n0]     = __builtin_amdgcn_mfma_f32_16x16x32_bf16(AH[q], BL0, acc[n0],     0, 0, 0);
            acc[n0 + 1] = __builtin_amdgcn_mfma_f32_16x16x32_bf16(AH[q], BL1, acc[n0 + 1], 0, 0, 0);
            acc[n0]     = __builtin_amdgcn_mfma_f32_16x16x32_bf16(AL[q], BH0, acc[n0],     0, 0, 0);
            acc[n0 + 1] = __builtin_amdgcn_mfma_f32_16x16x32_bf16(AL[q], BH1, acc[n0 + 1], 0, 0, 0);
            acc[n0]     = __builtin_amdgcn_mfma_f32_16x16x32_bf16(AL[q], BL0, acc[n0],     0, 0, 0);
            acc[n0 + 1] = __builtin_amdgcn_mfma_f32_16x16x32_bf16(AL[q], BL1, acc[n0 + 1], 0, 0, 0);
        }
    }

    // D: row = c0 + lq*4 + r, col = px0 + n*16 + lr
    float* ob = mixed + ((size_t)b * NCH + c0 + lq * 4) * NPIX + px0 + lr;
    #pragma unroll
    for (int n = 0; n < 8; ++n)
        #pragma unroll
        for (int r = 0; r < 4; ++r)
            ob[(size_t)r * NPIX + n * 16] = acc[n][r];
}

__device__ inline float clamp01(float z) { return fminf(fmaxf(z, 0.f), 1.f); }

// ---------------- bilinear affine sample (zero-halo LDS plane) ----------------
// As before (R6: 512 thr, 38.4KB LDS, 4 blocks/CU). NEW: WRITEP packs v as
// u32(hi|lo) in-place over this plane's `mixed` storage (read-set fully staged
// into LDS before the barrier -> overwrite safe) for the next layer's MFMA mix.
template<bool RES, bool POOL, bool WRITEP>
__global__ __launch_bounds__(512) void sample_kernel(const float* __restrict__ mixed,
                                                     const float* __restrict__ geo,
                                                     const float* __restrict__ box,
                                                     float* __restrict__ out,
                                                     float* __restrict__ pooled,
                                                     uint32_t* xpw) {
    __shared__ float m[HP * HP];
    const int c = blockIdx.x;
    const int b = blockIdx.y;
    const int t = threadIdx.x;
    if (t < HP) {
        m[t] = 0.f;
        m[(HP - 1) * HP + t] = 0.f;
    } else if (t < HP + 96) {
        const int h = t - HP + 1;
        m[h * HP] = 0.f;
        m[h * HP + HP - 1] = 0.f;
    }
    const float* src = mixed + ((size_t)b * NCH + c) * NPIX;
    #pragma unroll
    for (int r = 0; r < NPIX / 512; ++r) {
        const int idx = r * 512 + t;
        const int h = idx / 96, w = idx - (idx / 96) * 96;
        m[(h + 1) * HP + (w + 1)] = src[idx];
    }
    const float* gth = geo + c * 6;
    const float* bth = box + c * 6;
    const float g0 = gth[0], g1 = gth[1], g3 = gth[3], g4 = gth[4];
    const float gcx = 48.f * gth[2] - 47.5f * (g0 + g1) + 47.5f;
    const float gcy = 48.f * gth[5] - 47.5f * (g3 + g4) + 47.5f;
    const float b0 = bth[0], b1 = bth[1], b3 = bth[3], b4 = bth[4];
    const float bcx = 48.f * bth[2] - 47.5f * (b0 + b1) + 47.5f;
    const float bcy = 48.f * bth[5] - 47.5f * (b3 + b4) + 47.5f;
    float* o = out + ((size_t)b * NCH + c) * NPIX;
    uint32_t* xp = xpw + ((size_t)b * NCH + c) * NPIX;
    __syncthreads();
    float psum = 0.f;
    #pragma unroll 6
    for (int r = 0; r < NPIX / 512; ++r) {
        const int p = r * 512 + t;
        const int h = p / 96, w = p - (p / 96) * 96;
        const float fw = (float)w, fh = (float)h;
        float ix = fmaf(g0, fw, fmaf(g1, fh, gcx));
        float iy = fmaf(g3, fw, fmaf(g4, fh, gcy));
        ix = fminf(fmaxf(ix, -1.f), 96.f);
        iy = fminf(fmaxf(iy, -1.f), 96.f);
        const float x0f = floorf(ix), y0f = floorf(iy);
        const float fx = ix - x0f, fy = iy - y0f;
        const int base = ((int)y0f + 1) * HP + ((int)x0f + 1);
        const float m00 = m[base],      m01 = m[base + 1];
        const float m10 = m[base + HP], m11 = m[base + HP + 1];
        const float mx0 = fmaf(fx, m01 - m00, m00);
        const float mx1 = fmaf(fx, m11 - m10, m10);
        float v = fmaf(fy, mx1 - mx0, mx0);
        const float bx = fmaf(b0, fw, fmaf(b1, fh, bcx));
        const float by = fmaf(b3, fw, fmaf(b4, fh, bcy));
        const float Xs = fminf(clamp01(bx + 1.f), clamp01(96.f - bx));
        const float Ys = fminf(clamp01(by + 1.f), clamp01(96.f - by));
        v *= Xs * Ys;
        if (RES) v += o[p];
        o[p] = v;
        if (WRITEP) xp[p] = packbf(v);
        if (POOL) psum += v;
    }
    if (POOL) {
        #pragma unroll
        for (int off = 32; off > 0; off >>= 1) psum += __shfl_down(psum, off, 64);
        __shared__ float red[8];
        if ((t & 63) == 0) red[t >> 6] = psum;
        __syncthreads();
        if (t == 0) {
            float s = 0.f;
            #pragma unroll
            for (int i = 0; i < 8; ++i) s += red[i];
            pooled[b * NCH + c] = s * (1.f / (float)NPIX);
        }
    }
}

// ---------------- mean pool (fallback) ----------------
__global__ __launch_bounds__(256) void pool_kernel(const float* __restrict__ feat,
                                                   float* __restrict__ pooled) {
    const int bc = blockIdx.x;
    const float4* f = (const float4*)(feat + (size_t)bc * NPIX);
    float s = 0.f;
    for (int i = threadIdx.x; i < NPIX / 4; i += 256) {
        const float4 v = f[i];
        s += (v.x + v.y) + (v.z + v.w);
    }
    #pragma unroll
    for (int off = 32; off > 0; off >>= 1) s += __shfl_down(s, off, 64);
    __shared__ float red[4];
    if ((threadIdx.x & 63) == 0) red[threadIdx.x >> 6] = s;
    __syncthreads();
    if (threadIdx.x == 0)
        pooled[bc] = (red[0] + red[1] + red[2] + red[3]) * (1.f / (float)NPIX);
}

// ---------------- dense ----------------
__global__ __launch_bounds__(256) void dense_kernel(const float* __restrict__ pooled,
                                                    const float* __restrict__ Wt,
                                                    const float* __restrict__ bias,
                                                    float* __restrict__ out) {
    const int idx = blockIdx.x * 256 + threadIdx.x;
    if (idx >= NB * 1000) return;
    const int b = idx / 1000, n = idx - b * 1000;
    float acc = bias[n];
    const float* p = pooled + b * NCH;
    const float* wr = Wt + n * NCH;
    #pragma unroll 4
    for (int c = 0; c < NCH; ++c) acc = fmaf(p[c], wr[c], acc);
    out[idx] = acc;
}

extern "C" void kernel_launch(void* const* d_in, const int* in_sizes, int n_in,
                              void* d_out, int out_size, void* d_ws, size_t ws_size,
                              hipStream_t stream) {
    const float* x       = (const float*)d_in[0];
    const float* in_geo  = (const float*)d_in[1];
    const float* in_box  = (const float*)d_in[2];
    const float* in_lin  = (const float*)d_in[3];
    const float* lay_geo = (const float*)d_in[4];
    const float* lay_box = (const float*)d_in[5];
    const float* lay_lin = (const float*)d_in[6];
    const float* dense_w = (const float*)d_in[7];
    const float* dense_b = (const float*)d_in[8];

    float* out  = (float*)d_out;
    float* feat = out + NB * 1000;
    float* mixed = (float*)d_ws;

    const size_t mixedFloats = (size_t)NB * NCH * NPIX;
    const bool fusedPool = ws_size >= (mixedFloats + NB * NCH) * sizeof(float);
    const bool mfmaOK    = ws_size >= (mixedFloats + NB * NCH + 4 * NCH * NCH) * sizeof(float);
    float* pooled = fusedPool ? (float*)d_ws + mixedFloats : (float*)d_ws;

    const dim3 mixGrid(NPIX / 128, NB);
    const dim3 smpGrid(NCH, NB);

    if (mfmaOK) {
        uint32_t* xP   = (uint32_t*)d_ws;                               // aliases mixed (in-place)
        uint32_t* linP = (uint32_t*)((float*)d_ws + mixedFloats + NB * NCH);
        packlin_kernel<<<(4 * NCH * NCH + 255) / 256, 256, 0, stream>>>(lay_lin, linP, 4 * NCH * NCH);
        mix_kernel<64><<<mixGrid, 512, 0, stream>>>(x, in_lin, mixed);
        sample_kernel<false, false, true><<<smpGrid, 512, 0, stream>>>(mixed, in_geo, in_box, feat, pooled, xP);
        for (int i = 0; i < 3; ++i) {
            mix_mfma_kernel<<<mixGrid, 512, 0, stream>>>(xP, linP + (size_t)i * NCH * NCH, mixed);
            sample_kernel<true, false, true><<<smpGrid, 512, 0, stream>>>(mixed, lay_geo + i * NCH * 6,
                                                                          lay_box + i * NCH * 6, feat, pooled, xP);
        }
        mix_mfma_kernel<<<mixGrid, 512, 0, stream>>>(xP, linP + (size_t)3 * NCH * NCH, mixed);
        sample_kernel<true, true, false><<<smpGrid, 512, 0, stream>>>(mixed, lay_geo + 3 * NCH * 6,
                                                                      lay_box + 3 * NCH * 6, feat, pooled, xP);
    } else {
        uint32_t* dummy = (uint32_t*)d_ws;
        mix_kernel<64><<<mixGrid, 512, 0, stream>>>(x, in_lin, mixed);
        sample_kernel<false, false, false><<<smpGrid, 512, 0, stream>>>(mixed, in_geo, in_box, feat, pooled, dummy);
        for (int i = 0; i < 3; ++i) {
            mix_kernel<128><<<mixGrid, 512, 0, stream>>>(feat, lay_lin + i * NCH * NCH, mixed);
            sample_kernel<true, false, false><<<smpGrid, 512, 0, stream>>>(mixed, lay_geo + i * NCH * 6,
                                                                           lay_box + i * NCH * 6, feat, pooled, dummy);
        }
        mix_kernel<128><<<mixGrid, 512, 0, stream>>>(feat, lay_lin + 3 * NCH * NCH, mixed);
        if (fusedPool) {
            sample_kernel<true, true, false><<<smpGrid, 512, 0, stream>>>(mixed, lay_geo + 3 * NCH * 6,
                                                                          lay_box + 3 * NCH * 6, feat, pooled, dummy);
        } else {
            sample_kernel<true, false, false><<<smpGrid, 512, 0, stream>>>(mixed, lay_geo + 3 * NCH * 6,
                                                                           lay_box + 3 * NCH * 6, feat, pooled, dummy);
            pool_kernel<<<NB * NCH, 256, 0, stream>>>(feat, pooled);
        }
    }
    dense_kernel<<<(NB * 1000 + 255) / 256, 256, 0, stream>>>(pooled, dense_w, dense_b, out);
}

// Round 10
// 482.738 us; speedup vs baseline: 1.3227x; 1.0120x over previous
//
#include <hip/hip_runtime.h>
#include <stdint.h>

#define HW 96
#define NPIX 9216      // 96*96
#define NCH 128
#define NB 16
#define HP 98          // haloed plane dim (coords -1..96)

using bf16x8 = __attribute__((ext_vector_type(8))) short;   // 8 bf16 (4 VGPR) MFMA operand
using f32x4  = __attribute__((ext_vector_type(4))) float;   // MFMA accumulator

// pack fp32 -> (bf16_hi << 16) | bf16_lo, both RNE. hi+lo represents v to ~4e-6 rel.
__device__ inline uint32_t packbf(float v) {
    uint32_t u  = __float_as_uint(v);
    uint32_t rh = (u + 0x7FFFu + ((u >> 16) & 1u)) & 0xFFFF0000u;  // hi bf16, kept in fp32 position
    float    lo = v - __uint_as_float(rh);
    uint32_t ul = __float_as_uint(lo);
    uint32_t rl = ((ul + 0x7FFFu + ((ul >> 16) & 1u)) >> 16) & 0xFFFFu;
    return rh | rl;
}

// ---------------- tiny: pack lin fp32 -> u32(hi|lo) ----------------
__global__ __launch_bounds__(256) void packlin_kernel(const float* __restrict__ lin,
                                                      uint32_t* __restrict__ linP, int n) {
    const int i = blockIdx.x * 256 + threadIdx.x;
    if (i < n) linP[i] = packbf(lin[i]);
}

// ---------------- fp32 channel mix (fallback only) ----------------
template<int K>
__global__ __launch_bounds__(512, 4) void mix_kernel(const float* __restrict__ x,
                                                     const float* __restrict__ lin,
                                                     float* __restrict__ mixed) {
    const int b    = blockIdx.y;
    const int lane = threadIdx.x & 63;
    const int p    = blockIdx.x * 128 + lane * 2;
    const int c0   = __builtin_amdgcn_readfirstlane((threadIdx.x >> 6) * 16);
    const float* xb = x + (size_t)b * K * NPIX + p;
    const float* lr = lin + c0 * K;

    float2 acc[16];
    #pragma unroll
    for (int c = 0; c < 16; ++c) acc[c] = float2{0.f, 0.f};

    for (int k0 = 0; k0 < K; k0 += 8) {
        float2 xv[8];
        #pragma unroll
        for (int j = 0; j < 8; ++j)
            xv[j] = *(const float2*)&xb[(size_t)(k0 + j) * NPIX];
        #pragma unroll
        for (int c = 0; c < 16; ++c) {
            const float* lc = lr + c * K + k0;
            #pragma unroll
            for (int j = 0; j < 8; ++j) {
                acc[c].x = fmaf(lc[j], xv[j].x, acc[c].x);
                acc[c].y = fmaf(lc[j], xv[j].y, acc[c].y);
            }
        }
    }
    float* ob = mixed + (size_t)b * NCH * NPIX + p;
    #pragma unroll
    for (int c = 0; c < 16; ++c)
        *(float2*)&ob[(size_t)(c0 + c) * NPIX] = acc[c];
}

// ---------------- MFMA channel mix: mixed[b,c,p] = sum_k lin[c,k] * xf[b,k,p] ----------------
// R14-verified structure, generalized over K and fed fp32 directly (R15): the
// staging loop loads float4 from xf and packs to u32(hi|lo) in-registers
// (packbf), eliminating the xP packed mirror and its 73.7MB/sample write.
// bf16 hi/lo split on 16x16x32 MFMA (4 products, fp32-quality ~4e-6 rel).
// Block 512 = 8 waves; wave = 16ch x 128px; x tile [K x 128] in LDS, XOR-
// swizzled (px ^ ((k&0xC)<<2)) -> 2-way bank alias = free. Inner loop LDS+regs
// only (R11 lgkmcnt lesson). Frag maps verified by R14's pass:
// A: row=l&15, k=q*32+(e>>2)*16+(l>>4)*4+(e&3); B: col=l&15 same k; D: col=l&15,
// row=(l>>4)*4+r.
template<int K>
__global__ __launch_bounds__(512, 2) void mix_mfma_kernel(const float* __restrict__ xf,
                                                          const uint32_t* __restrict__ lp,
                                                          float* __restrict__ mixed) {
    __shared__ uint32_t xs[K * 128];       // K=128: 64KB (2 blocks/CU); K=64: 32KB
    const int b   = blockIdx.y;
    const int px0 = blockIdx.x * 128;
    const int t   = threadIdx.x;

    // ---- stage fp32 x tile, packing to hi|lo; swizzled: xs[k*128 + (px ^ ((k&0xC)<<2))] ----
    const float* xb = xf + (size_t)b * K * NPIX + px0;
    #pragma unroll
    for (int i = 0; i < K / 16; ++i) {
        const int f4  = i * 512 + t;
        const int row = f4 >> 5;
        const int c4  = (f4 & 31) << 2;
        const float4 v = *(const float4*)&xb[(size_t)row * NPIX + c4];
        uint4 pv;
        pv.x = packbf(v.x); pv.y = packbf(v.y); pv.z = packbf(v.z); pv.w = packbf(v.w);
        *(uint4*)&xs[row * 128 + (c4 ^ ((row & 0xC) << 2))] = pv;
    }

    const int l  = t & 63;
    const int wv = t >> 6;           // 0..7 -> channel group
    const int c0 = wv * 16;
    const int lq = l >> 4;           // lane quadrant
    const int lr = l & 15;

    // ---- A fragments (lin hi/lo) for K/32 K-steps, from packed linP[c][k] ----
    constexpr int NQ = K / 32;
    bf16x8 AH[NQ], AL[NQ];
    const uint32_t* lrow = lp + (size_t)(c0 + lr) * K;
    #pragma unroll
    for (int q = 0; q < NQ; ++q) {
        const uint4 a0 = *(const uint4*)&lrow[q * 32 + lq * 4];        // k half 0
        const uint4 a1 = *(const uint4*)&lrow[q * 32 + 16 + lq * 4];   // k half 1
        union { uint32_t w[4]; bf16x8 v; } h, m;
        h.w[0] = (a0.x >> 16) | (a0.y & 0xFFFF0000u);
        h.w[1] = (a0.z >> 16) | (a0.w & 0xFFFF0000u);
        h.w[2] = (a1.x >> 16) | (a1.y & 0xFFFF0000u);
        h.w[3] = (a1.z >> 16) | (a1.w & 0xFFFF0000u);
        m.w[0] = (a0.x & 0xFFFFu) | (a0.y << 16);
        m.w[1] = (a0.z & 0xFFFFu) | (a0.w << 16);
        m.w[2] = (a1.x & 0xFFFFu) | (a1.y << 16);
        m.w[3] = (a1.z & 0xFFFFu) | (a1.w << 16);
        AH[q] = h.v; AL[q] = m.v;
    }

    f32x4 acc[8];
    #pragma unroll
    for (int n = 0; n < 8; ++n) acc[n] = f32x4{0.f, 0.f, 0.f, 0.f};

    __syncthreads();

    const int pswz = lq << 4;        // == ((k&0xC)<<2) for every k this lane touches
    #pragma unroll
    for (int q = 0; q < NQ; ++q) {
        const int kb = q * 32 + lq * 4;
        #pragma unroll
        for (int np = 0; np < 4; ++np) {
            const int n0 = np * 2;
            bf16x8 BH0, BL0, BH1, BL1;
            #pragma unroll
            for (int s = 0; s < 2; ++s) {
                const int px = ((n0 + s) * 16 + lr) ^ pswz;
                const uint32_t u0 = xs[(kb + 0) * 128 + px];
                const uint32_t u1 = xs[(kb + 1) * 128 + px];
                const uint32_t u2 = xs[(kb + 2) * 128 + px];
                const uint32_t u3 = xs[(kb + 3) * 128 + px];
                const uint32_t u4 = xs[(kb + 16) * 128 + px];
                const uint32_t u5 = xs[(kb + 17) * 128 + px];
                const uint32_t u6 = xs[(kb + 18) * 128 + px];
                const uint32_t u7 = xs[(kb + 19) * 128 + px];
                union { uint32_t w[4]; bf16x8 v; } h, m;
                h.w[0] = (u0 >> 16) | (u1 & 0xFFFF0000u);
                h.w[1] = (u2 >> 16) | (u3 & 0xFFFF0000u);
                h.w[2] = (u4 >> 16) | (u5 & 0xFFFF0000u);
                h.w[3] = (u6 >> 16) | (u7 & 0xFFFF0000u);
                m.w[0] = (u0 & 0xFFFFu) | (u1 << 16);
                m.w[1] = (u2 & 0xFFFFu) | (u3 << 16);
                m.w[2] = (u4 & 0xFFFFu) | (u5 << 16);
                m.w[3] = (u6 & 0xFFFFu) | (u7 << 16);
                if (s == 0) { BH0 = h.v; BL0 = m.v; } else { BH1 = h.v; BL1 = m.v; }
            }
            acc[n0]     = __builtin_amdgcn_mfma_f32_16x16x32_bf16(AH[q], BH0, acc[n0],     0, 0, 0);
            acc[n0 + 1] = __builtin_amdgcn_mfma_f32_16x16x32_bf16(AH[q], BH1, acc[n0 + 1], 0, 0, 0);
            acc[n0]     = __builtin_amdgcn_mfma_f32_16x16x32_bf16(AH[q], BL0, acc[n0],     0, 0, 0);
            acc[n0 + 1] = __builtin_amdgcn_mfma_f32_16x16x32_bf16(AH[q], BL1, acc[n0 + 1], 0, 0, 0);
            acc[n0]     = __builtin_amdgcn_mfma_f32_16x16x32_bf16(AL[q], BH0, acc[n0],     0, 0, 0);
            acc[n0 + 1] = __builtin_amdgcn_mfma_f32_16x16x32_bf16(AL[q], BH1, acc[n0 + 1], 0, 0, 0);
            acc[n0]     = __builtin_amdgcn_mfma_f32_16x16x32_bf16(AL[q], BL0, acc[n0],     0, 0, 0);
            acc[n0 + 1] = __builtin_amdgcn_mfma_f32_16x16x32_bf16(AL[q], BL1, acc[n0 + 1], 0, 0, 0);
        }
    }

    // D: row = c0 + lq*4 + r, col = px0 + n*16 + lr
    float* ob = mixed + ((size_t)b * NCH + c0 + lq * 4) * NPIX + px0 + lr;
    #pragma unroll
    for (int n = 0; n < 8; ++n)
        #pragma unroll
        for (int r = 0; r < 4; ++r)
            ob[(size_t)r * NPIX + n * 16] = acc[n][r];
}

__device__ inline float clamp01(float z) { return fminf(fmaxf(z, 0.f), 1.f); }

// ---------------- bilinear affine sample (zero-halo LDS plane) ----------------
// R15: WRITEP removed (xP eliminated) -> WRITE_SIZE back to 73.7MB and the
// per-layer working set (~220MB) fits the 256MB L3.
template<bool RES, bool POOL>
__global__ __launch_bounds__(512) void sample_kernel(const float* __restrict__ mixed,
                                                     const float* __restrict__ geo,
                                                     const float* __restrict__ box,
                                                     float* __restrict__ out,
                                                     float* __restrict__ pooled) {
    __shared__ float m[HP * HP];
    const int c = blockIdx.x;
    const int b = blockIdx.y;
    const int t = threadIdx.x;
    if (t < HP) {
        m[t] = 0.f;
        m[(HP - 1) * HP + t] = 0.f;
    } else if (t < HP + 96) {
        const int h = t - HP + 1;
        m[h * HP] = 0.f;
        m[h * HP + HP - 1] = 0.f;
    }
    const float* src = mixed + ((size_t)b * NCH + c) * NPIX;
    #pragma unroll
    for (int r = 0; r < NPIX / 512; ++r) {
        const int idx = r * 512 + t;
        const int h = idx / 96, w = idx - (idx / 96) * 96;
        m[(h + 1) * HP + (w + 1)] = src[idx];
    }
    const float* gth = geo + c * 6;
    const float* bth = box + c * 6;
    const float g0 = gth[0], g1 = gth[1], g3 = gth[3], g4 = gth[4];
    const float gcx = 48.f * gth[2] - 47.5f * (g0 + g1) + 47.5f;
    const float gcy = 48.f * gth[5] - 47.5f * (g3 + g4) + 47.5f;
    const float b0 = bth[0], b1 = bth[1], b3 = bth[3], b4 = bth[4];
    const float bcx = 48.f * bth[2] - 47.5f * (b0 + b1) + 47.5f;
    const float bcy = 48.f * bth[5] - 47.5f * (b3 + b4) + 47.5f;
    float* o = out + ((size_t)b * NCH + c) * NPIX;
    __syncthreads();
    float psum = 0.f;
    #pragma unroll 6
    for (int r = 0; r < NPIX / 512; ++r) {
        const int p = r * 512 + t;
        const int h = p / 96, w = p - (p / 96) * 96;
        const float fw = (float)w, fh = (float)h;
        float ix = fmaf(g0, fw, fmaf(g1, fh, gcx));
        float iy = fmaf(g3, fw, fmaf(g4, fh, gcy));
        ix = fminf(fmaxf(ix, -1.f), 96.f);
        iy = fminf(fmaxf(iy, -1.f), 96.f);
        const float x0f = floorf(ix), y0f = floorf(iy);
        const float fx = ix - x0f, fy = iy - y0f;
        const int base = ((int)y0f + 1) * HP + ((int)x0f + 1);
        const float m00 = m[base],      m01 = m[base + 1];
        const float m10 = m[base + HP], m11 = m[base + HP + 1];
        const float mx0 = fmaf(fx, m01 - m00, m00);
        const float mx1 = fmaf(fx, m11 - m10, m10);
        float v = fmaf(fy, mx1 - mx0, mx0);
        const float bx = fmaf(b0, fw, fmaf(b1, fh, bcx));
        const float by = fmaf(b3, fw, fmaf(b4, fh, bcy));
        const float Xs = fminf(clamp01(bx + 1.f), clamp01(96.f - bx));
        const float Ys = fminf(clamp01(by + 1.f), clamp01(96.f - by));
        v *= Xs * Ys;
        if (RES) v += o[p];
        o[p] = v;
        if (POOL) psum += v;
    }
    if (POOL) {
        #pragma unroll
        for (int off = 32; off > 0; off >>= 1) psum += __shfl_down(psum, off, 64);
        __shared__ float red[8];
        if ((t & 63) == 0) red[t >> 6] = psum;
        __syncthreads();
        if (t == 0) {
            float s = 0.f;
            #pragma unroll
            for (int i = 0; i < 8; ++i) s += red[i];
            pooled[b * NCH + c] = s * (1.f / (float)NPIX);
        }
    }
}

// ---------------- mean pool (fallback) ----------------
__global__ __launch_bounds__(256) void pool_kernel(const float* __restrict__ feat,
                                                   float* __restrict__ pooled) {
    const int bc = blockIdx.x;
    const float4* f = (const float4*)(feat + (size_t)bc * NPIX);
    float s = 0.f;
    for (int i = threadIdx.x; i < NPIX / 4; i += 256) {
        const float4 v = f[i];
        s += (v.x + v.y) + (v.z + v.w);
    }
    #pragma unroll
    for (int off = 32; off > 0; off >>= 1) s += __shfl_down(s, off, 64);
    __shared__ float red[4];
    if ((threadIdx.x & 63) == 0) red[threadIdx.x >> 6] = s;
    __syncthreads();
    if (threadIdx.x == 0)
        pooled[bc] = (red[0] + red[1] + red[2] + red[3]) * (1.f / (float)NPIX);
}

// ---------------- dense ----------------
__global__ __launch_bounds__(256) void dense_kernel(const float* __restrict__ pooled,
                                                    const float* __restrict__ Wt,
                                                    const float* __restrict__ bias,
                                                    float* __restrict__ out) {
    const int idx = blockIdx.x * 256 + threadIdx.x;
    if (idx >= NB * 1000) return;
    const int b = idx / 1000, n = idx - b * 1000;
    float acc = bias[n];
    const float* p = pooled + b * NCH;
    const float* wr = Wt + n * NCH;
    #pragma unroll 4
    for (int c = 0; c < NCH; ++c) acc = fmaf(p[c], wr[c], acc);
    out[idx] = acc;
}

extern "C" void kernel_launch(void* const* d_in, const int* in_sizes, int n_in,
                              void* d_out, int out_size, void* d_ws, size_t ws_size,
                              hipStream_t stream) {
    const float* x       = (const float*)d_in[0];
    const float* in_geo  = (const float*)d_in[1];
    const float* in_box  = (const float*)d_in[2];
    const float* in_lin  = (const float*)d_in[3];
    const float* lay_geo = (const float*)d_in[4];
    const float* lay_box = (const float*)d_in[5];
    const float* lay_lin = (const float*)d_in[6];
    const float* dense_w = (const float*)d_in[7];
    const float* dense_b = (const float*)d_in[8];

    float* out  = (float*)d_out;
    float* feat = out + NB * 1000;
    float* mixed = (float*)d_ws;

    const size_t mixedFloats = (size_t)NB * NCH * NPIX;
    const size_t linPWords   = 4 * NCH * NCH + NCH * 64;    // lay_lin + in_lin packed
    const bool fusedPool = ws_size >= (mixedFloats + NB * NCH) * sizeof(float);
    const bool mfmaOK    = ws_size >= (mixedFloats + NB * NCH + linPWords) * sizeof(float);
    float* pooled = fusedPool ? (float*)d_ws + mixedFloats : (float*)d_ws;

    const dim3 mixGrid(NPIX / 128, NB);
    const dim3 smpGrid(NCH, NB);

    if (mfmaOK) {
        uint32_t* linP  = (uint32_t*)((float*)d_ws + mixedFloats + NB * NCH);
        uint32_t* linP0 = linP + 4 * NCH * NCH;             // packed in_lin [128][64]
        packlin_kernel<<<(4 * NCH * NCH + 255) / 256, 256, 0, stream>>>(lay_lin, linP, 4 * NCH * NCH);
        packlin_kernel<<<(NCH * 64 + 255) / 256, 256, 0, stream>>>(in_lin, linP0, NCH * 64);
        mix_mfma_kernel<64><<<mixGrid, 512, 0, stream>>>(x, linP0, mixed);
        sample_kernel<false, false><<<smpGrid, 512, 0, stream>>>(mixed, in_geo, in_box, feat, pooled);
        for (int i = 0; i < 3; ++i) {
            mix_mfma_kernel<128><<<mixGrid, 512, 0, stream>>>(feat, linP + (size_t)i * NCH * NCH, mixed);
            sample_kernel<true, false><<<smpGrid, 512, 0, stream>>>(mixed, lay_geo + i * NCH * 6,
                                                                    lay_box + i * NCH * 6, feat, pooled);
        }
        mix_mfma_kernel<128><<<mixGrid, 512, 0, stream>>>(feat, linP + (size_t)3 * NCH * NCH, mixed);
        sample_kernel<true, true><<<smpGrid, 512, 0, stream>>>(mixed, lay_geo + 3 * NCH * 6,
                                                               lay_box + 3 * NCH * 6, feat, pooled);
    } else {
        mix_kernel<64><<<mixGrid, 512, 0, stream>>>(x, in_lin, mixed);
        sample_kernel<false, false><<<smpGrid, 512, 0, stream>>>(mixed, in_geo, in_box, feat, pooled);
        for (int i = 0; i < 3; ++i) {
            mix_kernel<128><<<mixGrid, 512, 0, stream>>>(feat, lay_lin + i * NCH * NCH, mixed);
            sample_kernel<true, false><<<smpGrid, 512, 0, stream>>>(mixed, lay_geo + i * NCH * 6,
                                                                    lay_box + i * NCH * 6, feat, pooled);
        }
        mix_kernel<128><<<mixGrid, 512, 0, stream>>>(feat, lay_lin + 3 * NCH * NCH, mixed);
        if (fusedPool) {
            sample_kernel<true, true><<<smpGrid, 512, 0, stream>>>(mixed, lay_geo + 3 * NCH * 6,
                                                                   lay_box + 3 * NCH * 6, feat, pooled);
        } else {
            sample_kernel<true, false><<<smpGrid, 512, 0, stream>>>(mixed, lay_geo + 3 * NCH * 6,
                                                                    lay_box + 3 * NCH * 6, feat, pooled);
            pool_kernel<<<NB * NCH, 256, 0, stream>>>(feat, pooled);
        }
    }
    dense_kernel<<<(NB * 1000 + 255) / 256, 256, 0, stream>>>(pooled, dense_w, dense_b, out);
}

// Round 12
// 439.888 us; speedup vs baseline: 1.4515x; 1.0974x over previous
//
#include <hip/hip_runtime.h>
#include <hip/hip_bf16.h>
#include <stdint.h>

#define HW 96
#define NPIX 9216      // 96*96
#define NCH 128
#define NB 16
#define HP 98          // haloed plane dim (coords -1..96)

using bf16x8 = __attribute__((ext_vector_type(8))) short;   // 8 bf16 (4 VGPR) MFMA operand
using f32x4  = __attribute__((ext_vector_type(4))) float;   // MFMA accumulator

// pack fp32 -> (bf16_hi << 16) | bf16_lo, both RNE (integer-magic; used by packlin only)
__device__ inline uint32_t packbf(float v) {
    uint32_t u  = __float_as_uint(v);
    uint32_t rh = (u + 0x7FFFu + ((u >> 16) & 1u)) & 0xFFFF0000u;
    float    lo = v - __uint_as_float(rh);
    uint32_t ul = __float_as_uint(lo);
    uint32_t rl = ((ul + 0x7FFFu + ((ul >> 16) & 1u)) >> 16) & 0xFFFFu;
    return rh | rl;
}

// R16: cheap pack via HW bf16 cvt (compiler emits v_cvt_pk_bf16_f32, ~4 ops/elem
// vs 11 for the integer-magic version). hi = RNE(v), lo = RNE(v - hi): any-
// rounding-robust decomposition, rel err <= 2^-17.
__device__ inline uint32_t packbf_fast(float v) {
    __hip_bfloat16 h = __float2bfloat16(v);
    float hf = __bfloat162float(h);
    __hip_bfloat16 l = __float2bfloat16(v - hf);
    union { __hip_bfloat16 b; unsigned short u; } uh, ul;
    uh.b = h; ul.b = l;
    return ((uint32_t)uh.u << 16) | (uint32_t)ul.u;
}

// ---------------- tiny: pack lin fp32 -> u32(hi|lo) ----------------
__global__ __launch_bounds__(256) void packlin_kernel(const float* __restrict__ lin,
                                                      uint32_t* __restrict__ linP, int n) {
    const int i = blockIdx.x * 256 + threadIdx.x;
    if (i < n) linP[i] = packbf(lin[i]);
}

// ---------------- fp32 channel mix (fallback only) ----------------
template<int K>
__global__ __launch_bounds__(512, 4) void mix_kernel(const float* __restrict__ x,
                                                     const float* __restrict__ lin,
                                                     float* __restrict__ mixed) {
    const int b    = blockIdx.y;
    const int lane = threadIdx.x & 63;
    const int p    = blockIdx.x * 128 + lane * 2;
    const int c0   = __builtin_amdgcn_readfirstlane((threadIdx.x >> 6) * 16);
    const float* xb = x + (size_t)b * K * NPIX + p;
    const float* lr = lin + c0 * K;

    float2 acc[16];
    #pragma unroll
    for (int c = 0; c < 16; ++c) acc[c] = float2{0.f, 0.f};

    for (int k0 = 0; k0 < K; k0 += 8) {
        float2 xv[8];
        #pragma unroll
        for (int j = 0; j < 8; ++j)
            xv[j] = *(const float2*)&xb[(size_t)(k0 + j) * NPIX];
        #pragma unroll
        for (int c = 0; c < 16; ++c) {
            const float* lc = lr + c * K + k0;
            #pragma unroll
            for (int j = 0; j < 8; ++j) {
                acc[c].x = fmaf(lc[j], xv[j].x, acc[c].x);
                acc[c].y = fmaf(lc[j], xv[j].y, acc[c].y);
            }
        }
    }
    float* ob = mixed + (size_t)b * NCH * NPIX + p;
    #pragma unroll
    for (int c = 0; c < 16; ++c)
        *(float2*)&ob[(size_t)(c0 + c) * NPIX] = acc[c];
}

// ---------------- MFMA channel mix: mixed[b,c,p] = sum_k lin[c,k] * xf[b,k,p] ----------------
// R14-verified fragment maps; R15 fp32-direct staging (no xP mirror); R16:
// (1) packbf_fast staging pack, (2) k-split pipeline: stage half0 -> barrier ->
// ISSUE half1 loads -> compute q-half0 (LDS half0 only) -> pack+write half1
// (disjoint LDS region, no WAR) -> barrier -> compute q-half1. Hides half of
// the global-load + pack latency under MFMA compute (T14-lite).
// Frag maps: A: row=l&15, k=q*32+(e>>2)*16+(l>>4)*4+(e&3); B: col=l&15 same k;
// D: col=l&15, row=(l>>4)*4+r. XOR swizzle px ^ ((k&0xC)<<2) -> 2-way alias.
template<int K>
__global__ __launch_bounds__(512, 2) void mix_mfma_kernel(const float* __restrict__ xf,
                                                          const uint32_t* __restrict__ lp,
                                                          float* __restrict__ mixed) {
    __shared__ uint32_t xs[K * 128];       // K=128: 64KB (2 blocks/CU); K=64: 32KB
    const int b   = blockIdx.y;
    const int px0 = blockIdx.x * 128;
    const int t   = threadIdx.x;

    constexpr int NI = K / 16;             // float4-stage iterations (rows of 16 k)
    constexpr int NQ = K / 32;             // 32-k MFMA steps
    const float* xb = xf + (size_t)b * K * NPIX + px0;

    const int l  = t & 63;
    const int wv = t >> 6;           // 0..7 -> channel group
    const int c0 = wv * 16;
    const int lq = l >> 4;           // lane quadrant
    const int lr = l & 15;

    // ---- issue half-0 x loads (rows 0..K/2-1) ----
    float4 v0[NI / 2];
    #pragma unroll
    for (int i = 0; i < NI / 2; ++i) {
        const int f4  = i * 512 + t;
        const int row = f4 >> 5;
        const int c4  = (f4 & 31) << 2;
        v0[i] = *(const float4*)&xb[(size_t)row * NPIX + c4];
    }

    // ---- A fragments (lin hi/lo), overlap with x-load latency ----
    bf16x8 AH[NQ], AL[NQ];
    {
        const uint32_t* lrow = lp + (size_t)(c0 + lr) * K;
        #pragma unroll
        for (int q = 0; q < NQ; ++q) {
            const uint4 a0 = *(const uint4*)&lrow[q * 32 + lq * 4];        // k half 0
            const uint4 a1 = *(const uint4*)&lrow[q * 32 + 16 + lq * 4];   // k half 1
            union { uint32_t w[4]; bf16x8 v; } h, m;
            h.w[0] = (a0.x >> 16) | (a0.y & 0xFFFF0000u);
            h.w[1] = (a0.z >> 16) | (a0.w & 0xFFFF0000u);
            h.w[2] = (a1.x >> 16) | (a1.y & 0xFFFF0000u);
            h.w[3] = (a1.z >> 16) | (a1.w & 0xFFFF0000u);
            m.w[0] = (a0.x & 0xFFFFu) | (a0.y << 16);
            m.w[1] = (a0.z & 0xFFFFu) | (a0.w << 16);
            m.w[2] = (a1.x & 0xFFFFu) | (a1.y << 16);
            m.w[3] = (a1.z & 0xFFFFu) | (a1.w << 16);
            AH[q] = h.v; AL[q] = m.v;
        }
    }

    // ---- pack + write half 0 ----
    #pragma unroll
    for (int i = 0; i < NI / 2; ++i) {
        const int f4  = i * 512 + t;
        const int row = f4 >> 5;
        const int c4  = (f4 & 31) << 2;
        uint4 pv;
        pv.x = packbf_fast(v0[i].x); pv.y = packbf_fast(v0[i].y);
        pv.z = packbf_fast(v0[i].z); pv.w = packbf_fast(v0[i].w);
        *(uint4*)&xs[row * 128 + (c4 ^ ((row & 0xC) << 2))] = pv;
    }

    f32x4 acc[8];
    #pragma unroll
    for (int n = 0; n < 8; ++n) acc[n] = f32x4{0.f, 0.f, 0.f, 0.f};

    __syncthreads();

    const int pswz = lq << 4;        // == ((k&0xC)<<2) for every k this lane touches

    auto compute_q = [&](int q) {
        const int kb = q * 32 + lq * 4;
        #pragma unroll
        for (int np = 0; np < 4; ++np) {
            const int n0 = np * 2;
            bf16x8 BH0, BL0, BH1, BL1;
            #pragma unroll
            for (int s = 0; s < 2; ++s) {
                const int px = ((n0 + s) * 16 + lr) ^ pswz;
                const uint32_t u0 = xs[(kb + 0) * 128 + px];
                const uint32_t u1 = xs[(kb + 1) * 128 + px];
                const uint32_t u2 = xs[(kb + 2) * 128 + px];
                const uint32_t u3 = xs[(kb + 3) * 128 + px];
                const uint32_t u4 = xs[(kb + 16) * 128 + px];
                const uint32_t u5 = xs[(kb + 17) * 128 + px];
                const uint32_t u6 = xs[(kb + 18) * 128 + px];
                const uint32_t u7 = xs[(kb + 19) * 128 + px];
                union { uint32_t w[4]; bf16x8 v; } h, m;
                h.w[0] = (u0 >> 16) | (u1 & 0xFFFF0000u);
                h.w[1] = (u2 >> 16) | (u3 & 0xFFFF0000u);
                h.w[2] = (u4 >> 16) | (u5 & 0xFFFF0000u);
                h.w[3] = (u6 >> 16) | (u7 & 0xFFFF0000u);
                m.w[0] = (u0 & 0xFFFFu) | (u1 << 16);
                m.w[1] = (u2 & 0xFFFFu) | (u3 << 16);
                m.w[2] = (u4 & 0xFFFFu) | (u5 << 16);
                m.w[3] = (u6 & 0xFFFFu) | (u7 << 16);
                if (s == 0) { BH0 = h.v; BL0 = m.v; } else { BH1 = h.v; BL1 = m.v; }
            }
            acc[n0]     = __builtin_amdgcn_mfma_f32_16x16x32_bf16(AH[q], BH0, acc[n0],     0, 0, 0);
            acc[n0 + 1] = __builtin_amdgcn_mfma_f32_16x16x32_bf16(AH[q], BH1, acc[n0 + 1], 0, 0, 0);
            acc[n0]     = __builtin_amdgcn_mfma_f32_16x16x32_bf16(AH[q], BL0, acc[n0],     0, 0, 0);
            acc[n0 + 1] = __builtin_amdgcn_mfma_f32_16x16x32_bf16(AH[q], BL1, acc[n0 + 1], 0, 0, 0);
            acc[n0]     = __builtin_amdgcn_mfma_f32_16x16x32_bf16(AL[q], BH0, acc[n0],     0, 0, 0);
            acc[n0 + 1] = __builtin_amdgcn_mfma_f32_16x16x32_bf16(AL[q], BH1, acc[n0 + 1], 0, 0, 0);
            acc[n0]     = __builtin_amdgcn_mfma_f32_16x16x32_bf16(AL[q], BL0, acc[n0],     0, 0, 0);
            acc[n0 + 1] = __builtin_amdgcn_mfma_f32_16x16x32_bf16(AL[q], BL1, acc[n0 + 1], 0, 0, 0);
        }
    };

    // ---- issue half-1 x loads (rows K/2..K-1), then compute on half 0 ----
    float4 v1[NI / 2];
    #pragma unroll
    for (int i = 0; i < NI / 2; ++i) {
        const int f4  = (NI / 2 + i) * 512 + t;
        const int row = f4 >> 5;
        const int c4  = (f4 & 31) << 2;
        v1[i] = *(const float4*)&xb[(size_t)row * NPIX + c4];
    }

    #pragma unroll
    for (int q = 0; q < NQ / 2; ++q) compute_q(q);

    // ---- pack + write half 1 (disjoint LDS region; loads drained under compute) ----
    #pragma unroll
    for (int i = 0; i < NI / 2; ++i) {
        const int f4  = (NI / 2 + i) * 512 + t;
        const int row = f4 >> 5;
        const int c4  = (f4 & 31) << 2;
        uint4 pv;
        pv.x = packbf_fast(v1[i].x); pv.y = packbf_fast(v1[i].y);
        pv.z = packbf_fast(v1[i].z); pv.w = packbf_fast(v1[i].w);
        *(uint4*)&xs[row * 128 + (c4 ^ ((row & 0xC) << 2))] = pv;
    }
    __syncthreads();

    #pragma unroll
    for (int q = NQ / 2; q < NQ; ++q) compute_q(q);

    // D: row = c0 + lq*4 + r, col = px0 + n*16 + lr
    float* ob = mixed + ((size_t)b * NCH + c0 + lq * 4) * NPIX + px0 + lr;
    #pragma unroll
    for (int n = 0; n < 8; ++n)
        #pragma unroll
        for (int r = 0; r < 4; ++r)
            ob[(size_t)r * NPIX + n * 16] = acc[n][r];
}

__device__ inline float clamp01(float z) { return fminf(fmaxf(z, 0.f), 1.f); }

// ---------------- bilinear affine sample (zero-halo LDS plane) ----------------
template<bool RES, bool POOL>
__global__ __launch_bounds__(512) void sample_kernel(const float* __restrict__ mixed,
                                                     const float* __restrict__ geo,
                                                     const float* __restrict__ box,
                                                     float* __restrict__ out,
                                                     float* __restrict__ pooled) {
    __shared__ float m[HP * HP];
    const int c = blockIdx.x;
    const int b = blockIdx.y;
    const int t = threadIdx.x;
    if (t < HP) {
        m[t] = 0.f;
        m[(HP - 1) * HP + t] = 0.f;
    } else if (t < HP + 96) {
        const int h = t - HP + 1;
        m[h * HP] = 0.f;
        m[h * HP + HP - 1] = 0.f;
    }
    const float* src = mixed + ((size_t)b * NCH + c) * NPIX;
    #pragma unroll
    for (int r = 0; r < NPIX / 512; ++r) {
        const int idx = r * 512 + t;
        const int h = idx / 96, w = idx - (idx / 96) * 96;
        m[(h + 1) * HP + (w + 1)] = src[idx];
    }
    const float* gth = geo + c * 6;
    const float* bth = box + c * 6;
    const float g0 = gth[0], g1 = gth[1], g3 = gth[3], g4 = gth[4];
    const float gcx = 48.f * gth[2] - 47.5f * (g0 + g1) + 47.5f;
    const float gcy = 48.f * gth[5] - 47.5f * (g3 + g4) + 47.5f;
    const float b0 = bth[0], b1 = bth[1], b3 = bth[3], b4 = bth[4];
    const float bcx = 48.f * bth[2] - 47.5f * (b0 + b1) + 47.5f;
    const float bcy = 48.f * bth[5] - 47.5f * (b3 + b4) + 47.5f;
    float* o = out + ((size_t)b * NCH + c) * NPIX;
    __syncthreads();
    float psum = 0.f;
    #pragma unroll 6
    for (int r = 0; r < NPIX / 512; ++r) {
        const int p = r * 512 + t;
        const int h = p / 96, w = p - (p / 96) * 96;
        const float fw = (float)w, fh = (float)h;
        float ix = fmaf(g0, fw, fmaf(g1, fh, gcx));
        float iy = fmaf(g3, fw, fmaf(g4, fh, gcy));
        ix = fminf(fmaxf(ix, -1.f), 96.f);
        iy = fminf(fmaxf(iy, -1.f), 96.f);
        const float x0f = floorf(ix), y0f = floorf(iy);
        const float fx = ix - x0f, fy = iy - y0f;
        const int base = ((int)y0f + 1) * HP + ((int)x0f + 1);
        const float m00 = m[base],      m01 = m[base + 1];
        const float m10 = m[base + HP], m11 = m[base + HP + 1];
        const float mx0 = fmaf(fx, m01 - m00, m00);
        const float mx1 = fmaf(fx, m11 - m10, m10);
        float v = fmaf(fy, mx1 - mx0, mx0);
        const float bx = fmaf(b0, fw, fmaf(b1, fh, bcx));
        const float by = fmaf(b3, fw, fmaf(b4, fh, bcy));
        const float Xs = fminf(clamp01(bx + 1.f), clamp01(96.f - bx));
        const float Ys = fminf(clamp01(by + 1.f), clamp01(96.f - by));
        v *= Xs * Ys;
        if (RES) v += o[p];
        o[p] = v;
        if (POOL) psum += v;
    }
    if (POOL) {
        #pragma unroll
        for (int off = 32; off > 0; off >>= 1) psum += __shfl_down(psum, off, 64);
        __shared__ float red[8];
        if ((t & 63) == 0) red[t >> 6] = psum;
        __syncthreads();
        if (t == 0) {
            float s = 0.f;
            #pragma unroll
            for (int i = 0; i < 8; ++i) s += red[i];
            pooled[b * NCH + c] = s * (1.f / (float)NPIX);
        }
    }
}

// ---------------- mean pool (fallback) ----------------
__global__ __launch_bounds__(256) void pool_kernel(const float* __restrict__ feat,
                                                   float* __restrict__ pooled) {
    const int bc = blockIdx.x;
    const float4* f = (const float4*)(feat + (size_t)bc * NPIX);
    float s = 0.f;
    for (int i = threadIdx.x; i < NPIX / 4; i += 256) {
        const float4 v = f[i];
        s += (v.x + v.y) + (v.z + v.w);
    }
    #pragma unroll
    for (int off = 32; off > 0; off >>= 1) s += __shfl_down(s, off, 64);
    __shared__ float red[4];
    if ((threadIdx.x & 63) == 0) red[threadIdx.x >> 6] = s;
    __syncthreads();
    if (threadIdx.x == 0)
        pooled[bc] = (red[0] + red[1] + red[2] + red[3]) * (1.f / (float)NPIX);
}

// ---------------- dense ----------------
__global__ __launch_bounds__(256) void dense_kernel(const float* __restrict__ pooled,
                                                    const float* __restrict__ Wt,
                                                    const float* __restrict__ bias,
                                                    float* __restrict__ out) {
    const int idx = blockIdx.x * 256 + threadIdx.x;
    if (idx >= NB * 1000) return;
    const int b = idx / 1000, n = idx - b * 1000;
    float acc = bias[n];
    const float* p = pooled + b * NCH;
    const float* wr = Wt + n * NCH;
    #pragma unroll 4
    for (int c = 0; c < NCH; ++c) acc = fmaf(p[c], wr[c], acc);
    out[idx] = acc;
}

extern "C" void kernel_launch(void* const* d_in, const int* in_sizes, int n_in,
                              void* d_out, int out_size, void* d_ws, size_t ws_size,
                              hipStream_t stream) {
    const float* x       = (const float*)d_in[0];
    const float* in_geo  = (const float*)d_in[1];
    const float* in_box  = (const float*)d_in[2];
    const float* in_lin  = (const float*)d_in[3];
    const float* lay_geo = (const float*)d_in[4];
    const float* lay_box = (const float*)d_in[5];
    const float* lay_lin = (const float*)d_in[6];
    const float* dense_w = (const float*)d_in[7];
    const float* dense_b = (const float*)d_in[8];

    float* out  = (float*)d_out;
    float* feat = out + NB * 1000;
    float* mixed = (float*)d_ws;

    const size_t mixedFloats = (size_t)NB * NCH * NPIX;
    const size_t linPWords   = 4 * NCH * NCH + NCH * 64;    // lay_lin + in_lin packed
    const bool fusedPool = ws_size >= (mixedFloats + NB * NCH) * sizeof(float);
    const bool mfmaOK    = ws_size >= (mixedFloats + NB * NCH + linPWords) * sizeof(float);
    float* pooled = fusedPool ? (float*)d_ws + mixedFloats : (float*)d_ws;

    const dim3 mixGrid(NPIX / 128, NB);
    const dim3 smpGrid(NCH, NB);

    if (mfmaOK) {
        uint32_t* linP  = (uint32_t*)((float*)d_ws + mixedFloats + NB * NCH);
        uint32_t* linP0 = linP + 4 * NCH * NCH;             // packed in_lin [128][64]
        packlin_kernel<<<(4 * NCH * NCH + 255) / 256, 256, 0, stream>>>(lay_lin, linP, 4 * NCH * NCH);
        packlin_kernel<<<(NCH * 64 + 255) / 256, 256, 0, stream>>>(in_lin, linP0, NCH * 64);
        mix_mfma_kernel<64><<<mixGrid, 512, 0, stream>>>(x, linP0, mixed);
        sample_kernel<false, false><<<smpGrid, 512, 0, stream>>>(mixed, in_geo, in_box, feat, pooled);
        for (int i = 0; i < 3; ++i) {
            mix_mfma_kernel<128><<<mixGrid, 512, 0, stream>>>(feat, linP + (size_t)i * NCH * NCH, mixed);
            sample_kernel<true, false><<<smpGrid, 512, 0, stream>>>(mixed, lay_geo + i * NCH * 6,
                                                                    lay_box + i * NCH * 6, feat, pooled);
        }
        mix_mfma_kernel<128><<<mixGrid, 512, 0, stream>>>(feat, linP + (size_t)3 * NCH * NCH, mixed);
        sample_kernel<true, true><<<smpGrid, 512, 0, stream>>>(mixed, lay_geo + 3 * NCH * 6,
                                                               lay_box + 3 * NCH * 6, feat, pooled);
    } else {
        mix_kernel<64><<<mixGrid, 512, 0, stream>>>(x, in_lin, mixed);
        sample_kernel<false, false><<<smpGrid, 512, 0, stream>>>(mixed, in_geo, in_box, feat, pooled);
        for (int i = 0; i < 3; ++i) {
            mix_kernel<128><<<mixGrid, 512, 0, stream>>>(feat, lay_lin + i * NCH * NCH, mixed);
            sample_kernel<true, false><<<smpGrid, 512, 0, stream>>>(mixed, lay_geo + i * NCH * 6,
                                                                    lay_box + i * NCH * 6, feat, pooled);
        }
        mix_kernel<128><<<mixGrid, 512, 0, stream>>>(feat, lay_lin + 3 * NCH * NCH, mixed);
        if (fusedPool) {
            sample_kernel<true, true><<<smpGrid, 512, 0, stream>>>(mixed, lay_geo + 3 * NCH * 6,
                                                                   lay_box + 3 * NCH * 6, feat, pooled);
        } else {
            sample_kernel<true, false><<<smpGrid, 512, 0, stream>>>(mixed, lay_geo + 3 * NCH * 6,
                                                                    lay_box + 3 * NCH * 6, feat, pooled);
            pool_kernel<<<NB * NCH, 256, 0, stream>>>(feat, pooled);
        }
    }
    dense_kernel<<<(NB * 1000 + 255) / 256, 256, 0, stream>>>(pooled, dense_w, dense_b, out);
}